// Round 7
// baseline (400.849 us; speedup 1.0000x reference)
//
#include <hip/hip_runtime.h>

// VQ-VAE VectorQuantizer: B=32, C=D=64, H=W=64, K=512
// d_in[0]: inputs  [32,64,64,64] f32 (NCHW, C = embedding dim)
// d_in[1]: embedding [512,64] f32
// d_out: [loss(1) | out(32*64*64*64) | indices(32*4096)] all read as f32
//
// Numerics (verified passing R2/R4/R5/R6): comparator recomputes in numpy
// fp32: d_k = (x2 - 2*xe_k + e2_k)/64, argmin (first min). We replicate
// numpy's rounding: pairwise-8 sums for x2/e2 (squares rounded BEFORE add),
// then d = fl(fl(x2 - 2*xe) + e2), 4-chain FMA for xe. /64 dropped
// (argmin-invariant).
//
// R7: R2-R6 triangulated the bottleneck: every wave re-reads the whole 128KB
// codebook per pass (scalar path 262us, LDS path 336us, per-lane 550us) --
// broadcast operands save lanes, not per-wave delivery. Fix = invert layout:
//   * block of 512 threads = whole codebook; thread t holds code t's 64
//     components in VGPRs, loaded ONCE (asm-pinned; pin proven in R6).
//   * x becomes the wave-uniform operand, s_load'ed from a TRANSPOSED
//     [n][64] buffer (4 x s_load_dwordx16/position; SGPR operand bus is
//     free). Transpose kernel also computes np-exact x2 per position.
//   * argmin: 6-step shfl_xor fminf + ballot/ffs first-lane (== np
//     first-min), cross-wave reduce in ascending wave order, strict <.
// x_t lives in d_ws (34 MB for 1 slab; power-of-2 slab count picked from
// ws_size, deterministic -> graph-capture safe; R6 kernel kept as fallback
// if ws is tiny).

#define KCODE 512
#define EMB   64
#define HWSZ  4096          // H*W
#define BATCH 32
#define NPOS  (BATCH * HWSZ) // 131072
#define POSB  256            // positions per vq_main2 block

// numpy pairwise_sum leaf for n=64 (unrolled-by-8), squares NOT fused.
__device__ __forceinline__ float np_sumsq64(const float* a) {
    #pragma clang fp contract(off)
    {
        float r0 = a[0] * a[0], r1 = a[1] * a[1], r2 = a[2] * a[2], r3 = a[3] * a[3];
        float r4 = a[4] * a[4], r5 = a[5] * a[5], r6 = a[6] * a[6], r7 = a[7] * a[7];
        #pragma unroll
        for (int i = 8; i < 64; i += 8) {
            r0 += a[i + 0] * a[i + 0];
            r1 += a[i + 1] * a[i + 1];
            r2 += a[i + 2] * a[i + 2];
            r3 += a[i + 3] * a[i + 3];
            r4 += a[i + 4] * a[i + 4];
            r5 += a[i + 5] * a[i + 5];
            r6 += a[i + 6] * a[i + 6];
            r7 += a[i + 7] * a[i + 7];
        }
        return ((r0 + r1) + (r2 + r3)) + ((r4 + r5) + (r6 + r7));
    }
}

// ws (float view): ws[0]=loss accum; ws[8..519]=||e_k||^2; ws[1024..]=x2buf
// (slabN floats); then x_t (slabN*64 floats).
__global__ void vq_precompute(const float* __restrict__ emb, float* __restrict__ ws) {
    int k = blockIdx.x * blockDim.x + threadIdx.x;
    if (k == 0) ws[0] = 0.0f;
    if (k < KCODE) ws[8 + k] = np_sumsq64(emb + k * EMB);
}

// Transpose one slab of x into [n][64] layout + np-exact x2 per position.
// Block: 256 threads, 64 positions. Coalesced global reads and writes.
__global__ __launch_bounds__(256) void vq_transpose(
        const float* __restrict__ in, float* __restrict__ xt,
        float* __restrict__ x2buf, int slab_base) {
    __shared__ float tile[EMB][65];      // +1 pad
    const int t   = threadIdx.x;
    const int n0  = slab_base + blockIdx.x * 64;   // 64 | 4096 -> same b
    const int b   = n0 >> 12;
    const int hw0 = n0 & (HWSZ - 1);
    const float* ip = in + (size_t)b * (EMB * HWSZ) + hw0;
    const int hwl = t & 63;
    const int cq  = t >> 6;              // wave-uniform 0..3
    #pragma unroll
    for (int pass = 0; pass < 16; ++pass) {
        int c = cq + pass * 4;
        tile[c][hwl] = ip[(size_t)c * HWSZ + hwl];
    }
    __syncthreads();
    // write x_t: thread t -> position pl=t>>2, comps c0..c0+15 (fully coalesced)
    const int pl = t >> 2, c0 = (t & 3) * 16;
    float* op = xt + ((size_t)blockIdx.x * 64 + pl) * EMB + c0;
    #pragma unroll
    for (int j = 0; j < 16; j += 4) {
        float4 v = make_float4(tile[c0 + j][pl], tile[c0 + j + 1][pl],
                               tile[c0 + j + 2][pl], tile[c0 + j + 3][pl]);
        *(float4*)(op + j) = v;
    }
    // np-exact x2 for the 64 positions (threads 0..63)
    if (t < 64) {
        float a[EMB];
        #pragma unroll
        for (int c = 0; c < EMB; ++c) a[c] = tile[c][t];
        x2buf[blockIdx.x * 64 + t] = np_sumsq64(a);
    }
}

// Main kernel: block = 512 threads = 512 codes resident in VGPRs.
__attribute__((amdgpu_waves_per_eu(4, 4)))
__global__ __launch_bounds__(512) void vq_main2(
        const float* __restrict__ in,      // [32,64,4096] (epilogue x reads)
        const float* __restrict__ emb,     // [512,64] (epilogue gather)
        const float* __restrict__ e2,      // ws+8
        const float* __restrict__ xt,      // slab [slabN][64]
        const float* __restrict__ x2buf,   // slab [slabN]
        float* __restrict__ loss_accum,
        float* __restrict__ out_q,         // d_out+1
        float* __restrict__ out_idx,       // d_out+1+NPOS*EMB
        int slab_base) {
    const int t = threadIdx.x;           // == my code index
    const int w = t >> 6, l = t & 63;
    const int n0  = blockIdx.x * POSB;             // slab-local base
    const int gn0 = slab_base + n0;                // global position base
    const int b   = gn0 >> 12;
    const int hw0 = gn0 & (HWSZ - 1);

    // Codebook row -> VGPRs, ONCE; pin so it cannot be remat'd into the loop.
    float ce[EMB];
    #pragma unroll
    for (int c = 0; c < EMB; ++c) ce[c] = emb[(size_t)t * EMB + c];
    #pragma unroll
    for (int c = 0; c < EMB; ++c) asm volatile("" : "+v"(ce[c]));
    const float e2v = e2[t];

    __shared__ float sD[8][64];
    __shared__ int   sI[8][64];
    __shared__ int   sBest[64];
    __shared__ float red[8];

    float lossp = 0.0f;

    for (int g = 0; g < POSB / 64; ++g) {
        // ---- distance + per-wave argmin for 64 positions ----
        for (int pl = 0; pl < 64; ++pl) {
            const int p = (g << 6) | pl;
            const float* xs = xt + (size_t)(n0 + p) * EMB;  // block-uniform -> s_load
            const float x2 = x2buf[n0 + p];                 // uniform s_load
            float t0 = 0.f, t1 = 0.f, t2 = 0.f, t3 = 0.f;
            #pragma unroll
            for (int c = 0; c < EMB; c += 4) {
                t0 = fmaf(xs[c + 0], ce[c + 0], t0);
                t1 = fmaf(xs[c + 1], ce[c + 1], t1);
                t2 = fmaf(xs[c + 2], ce[c + 2], t2);
                t3 = fmaf(xs[c + 3], ce[c + 3], t3);
            }
            float xe  = (t0 + t1) + (t2 + t3);
            float tmp = x2 - 2.0f * xe;      // fl(x2-2xe): same order as R2
            float d   = tmp + e2v;           // fl(tmp+e2)
            // 64-lane min, then first lane achieving it (= np first-min)
            float dmin = d;
            #pragma unroll
            for (int off = 32; off > 0; off >>= 1)
                dmin = fminf(dmin, __shfl_xor(dmin, off, 64));
            unsigned long long m = __ballot(d == dmin);
            if (l == 0) {
                sD[w][pl] = dmin;
                sI[w][pl] = (w << 6) + (int)__ffsll((unsigned long long)m) - 1;
            }
        }
        __syncthreads();
        // ---- cross-wave reduce (ascending wave, strict < = first-min) ----
        if (t < 64) {
            float bd = sD[0][t];
            int   bi = sI[0][t];
            #pragma unroll
            for (int ww = 1; ww < 8; ++ww) {
                float dd = sD[ww][t];
                if (dd < bd) { bd = dd; bi = sI[ww][t]; }
            }
            sBest[t] = bi;
            out_idx[gn0 + (g << 6) + t] = (float)bi;
        }
        __syncthreads();
        // ---- quantized write + loss partial for the group ----
        const int hwg = hw0 + (g << 6);
        const int sbest = sBest[l];
        const float* inb  = in    + (size_t)b * (EMB * HWSZ);
        float*       outb = out_q + (size_t)b * (EMB * HWSZ);
        #pragma unroll
        for (int pass = 0; pass < 8; ++pass) {
            int c = w + (pass << 3);
            float ev = emb[(size_t)sbest * EMB + c];        // gather (L2-hot)
            float xv = inb[(size_t)c * HWSZ + hwg + l];     // coalesced
            outb[(size_t)c * HWSZ + hwg + l] = ev;          // coalesced
            float df = ev - xv;
            lossp = fmaf(df, df, lossp);
        }
        __syncthreads();   // sBest/sD reuse safety for next group
    }

    // ---- block loss reduction ----
    #pragma unroll
    for (int off = 32; off > 0; off >>= 1)
        lossp += __shfl_down(lossp, off, 64);
    if (l == 0) red[w] = lossp;
    __syncthreads();
    if (t == 0) {
        float bs = ((red[0] + red[1]) + (red[2] + red[3])) +
                   ((red[4] + red[5]) + (red[6] + red[7]));
        atomicAdd(loss_accum, bs);
    }
}

// ---- fallback (R6 structure) if d_ws is too small for any slab config ----
__attribute__((amdgpu_waves_per_eu(2, 2)))
__global__ __launch_bounds__(256) void vq_main_fb(
        const float* __restrict__ in, const float* __restrict__ emb,
        const float* __restrict__ e2, float* __restrict__ loss_accum,
        float* __restrict__ out_q, float* __restrict__ out_idx) {
    const int tid = threadIdx.x;
    const int n   = blockIdx.x * 256 + tid;
    const int b   = n >> 12;
    const int hw  = n & (HWSZ - 1);
    const float* xp = in + (size_t)b * (EMB * HWSZ) + hw;
    float x[EMB];
    #pragma unroll
    for (int c = 0; c < EMB; ++c) x[c] = xp[(size_t)c * HWSZ];
    #pragma unroll
    for (int c = 0; c < EMB; ++c) asm volatile("" : "+v"(x[c]));
    const float x2 = np_sumsq64(x);
    int   best  = 0;
    float bestD = 3.4e38f;
    #pragma unroll 2
    for (int k = 0; k < KCODE; ++k) {
        const float* ek = emb + k * EMB;
        float t0 = 0.f, t1 = 0.f, t2 = 0.f, t3 = 0.f;
        #pragma unroll
        for (int c = 0; c < EMB; c += 4) {
            t0 = fmaf(x[c + 0], ek[c + 0], t0);
            t1 = fmaf(x[c + 1], ek[c + 1], t1);
            t2 = fmaf(x[c + 2], ek[c + 2], t2);
            t3 = fmaf(x[c + 3], ek[c + 3], t3);
        }
        float xe  = (t0 + t1) + (t2 + t3);
        float tmp = x2 - 2.0f * xe;
        float d   = tmp + e2[k];
        if (d < bestD) { bestD = d; best = k; }
    }
    const float4* qk = (const float4*)(emb + (size_t)best * EMB);
    float* op = out_q + (size_t)b * (EMB * HWSZ) + hw;
    float s = 0.0f;
    #pragma unroll
    for (int c4 = 0; c4 < EMB / 4; ++c4) {
        float4 v = qk[c4];
        float d0 = v.x - x[c4 * 4 + 0];
        float d1 = v.y - x[c4 * 4 + 1];
        float d2 = v.z - x[c4 * 4 + 2];
        float d3 = v.w - x[c4 * 4 + 3];
        s = fmaf(d0, d0, s); s = fmaf(d1, d1, s);
        s = fmaf(d2, d2, s); s = fmaf(d3, d3, s);
        op[(size_t)(c4 * 4 + 0) * HWSZ] = v.x;
        op[(size_t)(c4 * 4 + 1) * HWSZ] = v.y;
        op[(size_t)(c4 * 4 + 2) * HWSZ] = v.z;
        op[(size_t)(c4 * 4 + 3) * HWSZ] = v.w;
    }
    out_idx[n] = (float)best;
    float ssum = s;
    #pragma unroll
    for (int off = 32; off > 0; off >>= 1)
        ssum += __shfl_down(ssum, off, 64);
    __shared__ float red[4];
    if ((tid & 63) == 0) red[tid >> 6] = ssum;
    __syncthreads();
    if (tid == 0) atomicAdd(loss_accum, (red[0] + red[1]) + (red[2] + red[3]));
}

__global__ void vq_finalize(const float* __restrict__ loss_accum,
                            float* __restrict__ out0) {
    out0[0] = 1.25f * loss_accum[0] * (1.0f / ((float)NPOS * (float)EMB));
}

extern "C" void kernel_launch(void* const* d_in, const int* in_sizes, int n_in,
                              void* d_out, int out_size, void* d_ws, size_t ws_size,
                              hipStream_t stream) {
    const float* in  = (const float*)d_in[0];
    const float* emb = (const float*)d_in[1];
    float* ws   = (float*)d_ws;
    float* out  = (float*)d_out;

    float* loss_accum = ws;
    float* e2         = ws + 8;
    float* out_loss   = out;
    float* out_q      = out + 1;
    float* out_idx    = out + 1 + (size_t)NPOS * EMB;

    vq_precompute<<<2, 256, 0, stream>>>(emb, ws);

    // Pick smallest slab count whose buffers fit in ws (deterministic in
    // ws_size -> graph-capture safe).
    int S = 0;
    for (int s = 1; s <= 32; s <<= 1) {
        size_t slabN = NPOS / s;
        size_t need  = (size_t)(1024 + slabN * 65) * 4;
        if (ws_size >= need) { S = s; break; }
    }
    if (S) {
        const int slabN = NPOS / S;
        float* x2buf = ws + 1024;
        float* xt    = ws + 1024 + slabN;
        for (int s = 0; s < S; ++s) {
            const int slab_base = s * slabN;
            vq_transpose<<<slabN / 64, 256, 0, stream>>>(in, xt, x2buf, slab_base);
            vq_main2<<<slabN / POSB, 512, 0, stream>>>(
                in, emb, e2, xt, x2buf, loss_accum, out_q, out_idx, slab_base);
        }
    } else {
        vq_main_fb<<<NPOS / 256, 256, 0, stream>>>(in, emb, e2, loss_accum,
                                                   out_q, out_idx);
    }
    vq_finalize<<<1, 1, 0, stream>>>(loss_accum, out_loss);
}